// Round 6
// baseline (82.131 us; speedup 1.0000x reference)
//
#include <hip/hip_runtime.h>
#include <hip/hip_bf16.h>
#include <stdint.h>

constexpr int FEAT  = 512;     // feature dim (K)
constexpr int EMB   = 256;     // embed dim   (M)
constexpr int BATCH = 16384;   // batch       (N)
constexpr int NSAMP = 10;
constexpr int NB    = 32;      // batch rows per block
constexpr int NW    = 4;       // waves per block
constexpr int RPW   = NB / NW; // 8 rows per wave
constexpr int CH    = RPW * NSAMP;  // 80 neighbor-chunks per wave
constexpr int RING  = 4;       // LDS ring slots per wave (2 KB each)
constexpr float SLOPE  = 11.0f / 48.0f;   // RReLU eval slope (1/8+1/3)/2
constexpr float INV_NS = 1.0f / 10.0f;

using f32x4 = __attribute__((ext_vector_type(4))) float;
using frag8 = __attribute__((ext_vector_type(8))) short;  // 8 bf16 (4 VGPRs)

static __device__ __forceinline__ unsigned bpack2(float a, float b) {
    // f32 pair -> packed bf16x2 (RNE); compiler lowers to v_cvt_pk_bf16_f32
    __hip_bfloat162 h = __float22bfloat162_rn(make_float2(a, b));
    unsigned u; __builtin_memcpy(&u, &h, 4);
    return u;
}

// One fused kernel: gather+mean (LDS-ring staged via global_load_lds for MLP)
// -> bf16 LDS tile (XOR-swizzled) -> MFMA GEMM -> RReLU. No workspace: every
// global READ is an immutable harness input (no R2 staleness class).
__global__ __launch_bounds__(256, 2) void enc_fused(const float* __restrict__ feat,
                                                    const float* __restrict__ wgt,
                                                    const int*   __restrict__ idx,
                                                    float*       __restrict__ out) {
    __shared__ float  Stage[NW][RING][FEAT];  // 32 KB: per-wave 4-slot ring, 2 KB rows
    __shared__ ushort Bs[NB * FEAT];          // 32 KB: agg tile, 1 KB rows, XOR-swizzled
    __shared__ int    IdxS[NW][CH];           // 1.25 KB: per-wave neighbor ids

    const int tid  = threadIdx.x;
    const int wv   = tid >> 6;
    const int lane = tid & 63;
    const int n0   = blockIdx.x * NB;

    // ---------------- phase 1: gather + mean -> Bs ----------------
    // Stage neighbor id list for this wave's 8 rows (80 consecutive ints).
    for (int f = lane; f < CH; f += 64)
        IdxS[wv][f] = idx[(size_t)(n0 + wv * RPW) * NSAMP + f];
    // (intra-wave LDS RAW: no barrier needed)

    auto issue = [&](int f) {
        const int nbr = IdxS[wv][f];
        const float* src = feat + (size_t)nbr * FEAT + lane * 4;
        float* dst = &Stage[wv][f & (RING - 1)][0];   // wave-uniform base; HW adds lane*16B
        __builtin_amdgcn_global_load_lds(
            (const __attribute__((address_space(1))) void*)src,
            (__attribute__((address_space(3))) void*)dst, 16, 0, 0);
        __builtin_amdgcn_global_load_lds(
            (const __attribute__((address_space(1))) void*)(src + 256),
            (__attribute__((address_space(3))) void*)(dst + 256), 16, 0, 0);
    };

#pragma unroll
    for (int f = 0; f < RING; ++f) issue(f);

    f32x4 s0 = {0.f, 0.f, 0.f, 0.f}, s1 = {0.f, 0.f, 0.f, 0.f};
#pragma unroll
    for (int rr = 0; rr < RPW; ++rr) {
#pragma unroll
        for (int j = 0; j < NSAMP; ++j) {
            const int f = rr * NSAMP + j;
            // chunk f ready once outstanding <= 2*(RING-1): counted vmcnt, never 0 in steady state
            if (f <= CH - RING) asm volatile("s_waitcnt vmcnt(6)" ::: "memory");
            else                asm volatile("s_waitcnt vmcnt(0)" ::: "memory");
            __builtin_amdgcn_sched_barrier(0);
            const float* sp = &Stage[wv][f & (RING - 1)][lane * 4];
            s0 += *reinterpret_cast<const f32x4*>(sp);
            s1 += *reinterpret_cast<const f32x4*>(sp + 256);
            __builtin_amdgcn_sched_barrier(0);      // reads precede slot-reuse DMA issue
            if (f + RING < CH) issue(f + RING);
            if (j == NSAMP - 1) {
                s0 *= INV_NS; s1 *= INV_NS;
                const int r   = wv * RPW + rr;
                const int swz = (r & 7) << 4;
                uint2 lo, hi;
                lo.x = bpack2(s0[0], s0[1]); lo.y = bpack2(s0[2], s0[3]);
                hi.x = bpack2(s1[0], s1[1]); hi.y = bpack2(s1[2], s1[3]);
                char* rowp = (char*)Bs + r * (FEAT * 2);
                *reinterpret_cast<uint2*>(rowp + ((lane * 8) ^ swz))       = lo;
                *reinterpret_cast<uint2*>(rowp + ((512 + lane * 8) ^ swz)) = hi;
                s0 = (f32x4){0.f, 0.f, 0.f, 0.f};
                s1 = (f32x4){0.f, 0.f, 0.f, 0.f};
            }
        }
    }
    __syncthreads();

    // ---------------- phase 2: out[m][n] = W[m,:].Agg[n,:], RReLU ----------------
    const int l15 = lane & 15, lq = lane >> 4;
    const int m0w = wv * 64;               // 4 waves split M=256 into 4x64

    f32x4 acc[4][2] = {};

#pragma unroll
    for (int k0 = 0; k0 < FEAT; k0 += 32) {
        frag8 af[4], bf[2];
#pragma unroll
        for (int i = 0; i < 4; ++i) {
            const float* wp = wgt + (size_t)(m0w + i * 16 + l15) * FEAT + k0 + lq * 8;
            const f32x4 a0 = *reinterpret_cast<const f32x4*>(wp);
            const f32x4 a1 = *reinterpret_cast<const f32x4*>(wp + 4);
            union { unsigned u[4]; frag8 f; } pk;
            pk.u[0] = bpack2(a0[0], a0[1]); pk.u[1] = bpack2(a0[2], a0[3]);
            pk.u[2] = bpack2(a1[0], a1[1]); pk.u[3] = bpack2(a1[2], a1[3]);
            af[i] = pk.f;
        }
#pragma unroll
        for (int jj = 0; jj < 2; ++jj) {
            const int row = jj * 16 + l15;
            const int kb  = (k0 * 2 + lq * 16) ^ ((row & 7) << 4);
            bf[jj] = *reinterpret_cast<const frag8*>((const char*)Bs + row * (FEAT * 2) + kb);
        }
#pragma unroll
        for (int i = 0; i < 4; ++i)
#pragma unroll
            for (int jj = 0; jj < 2; ++jj)
                acc[i][jj] = __builtin_amdgcn_mfma_f32_16x16x32_bf16(af[i], bf[jj], acc[i][jj], 0, 0, 0);
    }

    // epilogue: C/D layout col=lane&15, row=(lane>>4)*4+q (verified mapping)
#pragma unroll
    for (int i = 0; i < 4; ++i) {
        const int rb = m0w + i * 16 + lq * 4;
#pragma unroll
        for (int jj = 0; jj < 2; ++jj) {
            const int col = n0 + jj * 16 + l15;
#pragma unroll
            for (int q = 0; q < 4; ++q) {
                float y = acc[i][jj][q];
                y = (y >= 0.f) ? y : y * SLOPE;
                out[(size_t)(rb + q) * BATCH + col] = y;
            }
        }
    }
}

extern "C" void kernel_launch(void* const* d_in, const int* in_sizes, int n_in,
                              void* d_out, int out_size, void* d_ws, size_t ws_size,
                              hipStream_t stream) {
    const float* feat = (const float*)d_in[0];
    const float* wgt  = (const float*)d_in[1];
    const int*   idx  = (const int*)d_in[2];
    float*       out  = (float*)d_out;

    enc_fused<<<BATCH / NB, 256, 0, stream>>>(feat, wgt, idx, out);
}

// Round 7
// 67.164 us; speedup vs baseline: 1.2228x; 1.2228x over previous
//
#include <hip/hip_runtime.h>
#include <hip/hip_bf16.h>
#include <stdint.h>

constexpr int FEAT  = 512;     // feature dim (K)
constexpr int EMB   = 256;     // embed dim   (M)
constexpr int BATCH = 16384;   // batch       (N)
constexpr int NSAMP = 10;
constexpr int NB    = 64;      // batch rows per block
constexpr int NW    = 16;      // waves per block (1024 threads)
constexpr int RPW   = NB / NW; // 4 rows per wave
constexpr float SLOPE  = 11.0f / 48.0f;   // RReLU eval slope (1/8+1/3)/2
constexpr float INV_NS = 1.0f / 10.0f;

using f32x4 = __attribute__((ext_vector_type(4))) float;
using frag8 = __attribute__((ext_vector_type(8))) short;  // 8 bf16 (4 VGPRs)

static __device__ __forceinline__ unsigned bpack2(float a, float b) {
    // f32 pair -> packed bf16x2 (RNE); compiler lowers to v_cvt_pk_bf16_f32
    __hip_bfloat162 h = __float22bfloat162_rn(make_float2(a, b));
    unsigned u; __builtin_memcpy(&u, &h, 4);
    return u;
}

// One fused kernel: gather+mean -> bf16 LDS tile (XOR-swizzled) -> MFMA GEMM
// -> RReLU. No workspace: every global READ is an immutable harness input
// (no R2 cross-replay staleness class).
// 16 waves/block, grid = 1 block/CU: doubles gather memory-level parallelism
// vs R5 (8 waves/CU -> 16) while keeping W f32 re-read at 134 MB (L2-served).
__global__ __launch_bounds__(1024, 4) void enc_fused(const float* __restrict__ feat,
                                                     const float* __restrict__ wgt,
                                                     const int*   __restrict__ idx,
                                                     float*       __restrict__ out) {
    __shared__ ushort Bs[NB * FEAT];   // 64 KB; row-major 1KB rows, XOR-swizzled

    const int tid  = threadIdx.x;
    const int wv   = tid >> 6;
    const int lane = tid & 63;
    const int n0   = blockIdx.x * NB;

    // ---------------- phase 1: gather + mean -> Bs ----------------
    // wave wv owns rows wv*4 .. wv*4+3; lane covers 8 contiguous floats (32B).
#pragma unroll 2
    for (int rr = 0; rr < RPW; ++rr) {
        const int r  = wv * RPW + rr;
        const int ru = __builtin_amdgcn_readfirstlane(r);       // -> scalar idx loads
        const int* ib = idx + (size_t)(n0 + ru) * NSAMP;
        f32x4 s0 = {0.f, 0.f, 0.f, 0.f}, s1 = {0.f, 0.f, 0.f, 0.f};
#pragma unroll
        for (int j = 0; j < NSAMP; ++j) {
            const float* fp = feat + (size_t)ib[j] * FEAT + lane * 8;
            const f32x4 v0 = *reinterpret_cast<const f32x4*>(fp);
            const f32x4 v1 = *reinterpret_cast<const f32x4*>(fp + 4);
            s0 += v0; s1 += v1;
        }
        union { frag8 f; unsigned u[4]; } o;
        o.u[0] = bpack2(s0[0] * INV_NS, s0[1] * INV_NS);
        o.u[1] = bpack2(s0[2] * INV_NS, s0[3] * INV_NS);
        o.u[2] = bpack2(s1[0] * INV_NS, s1[1] * INV_NS);
        o.u[3] = bpack2(s1[2] * INV_NS, s1[3] * INV_NS);
        const int kb = (lane * 16) ^ ((r & 7) << 4);            // swizzled byte offset
        *reinterpret_cast<frag8*>((char*)Bs + r * (FEAT * 2) + kb) = o.f;
    }
    __syncthreads();

    // ---------------- phase 2: out[m][n] = W[m,:].Agg[n,:], RReLU ----------------
    const int l15 = lane & 15, lq = lane >> 4;
    const int m0w = wv * 16;               // 16 waves split M=256 into 16x16

    f32x4 acc[4] = {};

#pragma unroll
    for (int k0 = 0; k0 < FEAT; k0 += 32) {
        frag8 af, bf[4];
        {
            const float* wp = wgt + (size_t)(m0w + l15) * FEAT + k0 + lq * 8;
            const f32x4 a0 = *reinterpret_cast<const f32x4*>(wp);
            const f32x4 a1 = *reinterpret_cast<const f32x4*>(wp + 4);
            union { unsigned u[4]; frag8 f; } pk;
            pk.u[0] = bpack2(a0[0], a0[1]); pk.u[1] = bpack2(a0[2], a0[3]);
            pk.u[2] = bpack2(a1[0], a1[1]); pk.u[3] = bpack2(a1[2], a1[3]);
            af = pk.f;
        }
#pragma unroll
        for (int jj = 0; jj < 4; ++jj) {
            const int row = jj * 16 + l15;
            const int kb  = (k0 * 2 + lq * 16) ^ ((row & 7) << 4);
            bf[jj] = *reinterpret_cast<const frag8*>((const char*)Bs + row * (FEAT * 2) + kb);
        }
#pragma unroll
        for (int jj = 0; jj < 4; ++jj)
            acc[jj] = __builtin_amdgcn_mfma_f32_16x16x32_bf16(af, bf[jj], acc[jj], 0, 0, 0);
    }

    // epilogue: C/D layout col=lane&15, row=(lane>>4)*4+q (verified mapping)
#pragma unroll
    for (int jj = 0; jj < 4; ++jj) {
        const int col = n0 + jj * 16 + l15;
#pragma unroll
        for (int q = 0; q < 4; ++q) {
            const int row = m0w + lq * 4 + q;
            float y = acc[jj][q];
            y = (y >= 0.f) ? y : y * SLOPE;
            out[(size_t)row * BATCH + col] = y;
        }
    }
}

extern "C" void kernel_launch(void* const* d_in, const int* in_sizes, int n_in,
                              void* d_out, int out_size, void* d_ws, size_t ws_size,
                              hipStream_t stream) {
    const float* feat = (const float*)d_in[0];
    const float* wgt  = (const float*)d_in[1];
    const int*   idx  = (const int*)d_in[2];
    float*       out  = (float*)d_out;

    enc_fused<<<BATCH / NB, 1024, 0, stream>>>(feat, wgt, idx, out);
}